// Round 2
// baseline (359.584 us; speedup 1.0000x reference)
//
#include <hip/hip_runtime.h>

#define N_IN  128
#define N_OUT 64

// C0T[i][o] = sum_k Wfc[o][k]     * W0[k][i]   (transposed for coalesced reads)
// C12T[i][o]= sum_k Wfc[o][128+k] * W1[k][i] + Wfc[o][256+k] * W2[k][i]
__global__ void combine_weights(const float* __restrict__ W0,
                                const float* __restrict__ W1,
                                const float* __restrict__ W2,
                                const float* __restrict__ Wfc,
                                float* __restrict__ C0T,
                                float* __restrict__ C12T) {
    int t = blockIdx.x * blockDim.x + threadIdx.x;   // 8192 threads
    if (t >= N_IN * N_OUT) return;
    int o = t & (N_OUT - 1);
    int i = t >> 6;
    float a0 = 0.f, a12 = 0.f;
    for (int k = 0; k < 128; ++k) {
        a0  += Wfc[o * 384 + k]       * W0[k * N_IN + i];
        a12 += Wfc[o * 384 + 128 + k] * W1[k * N_IN + i]
             + Wfc[o * 384 + 256 + k] * W2[k * N_IN + i];
    }
    C0T[i * N_OUT + o]  = a0;
    C12T[i * N_OUT + o] = a12;
}

// edge_index passed as int32 by the harness (integer inputs -> const int*)
__global__ void degree_kernel(const int* __restrict__ ei,
                              float* __restrict__ deg, int E) {
    int e = blockIdx.x * blockDim.x + threadIdx.x;
    if (e < E) atomicAdd(&deg[ei[E + e]], 1.0f);
}

__global__ void rsqrt_kernel(float* __restrict__ deg, int N) {
    int n = blockIdx.x * blockDim.x + threadIdx.x;
    if (n < N) { float d = deg[n]; deg[n] = d > 0.f ? rsqrtf(d) : 0.f; }
}

// out[n] = x[n] @ C0T, y[n] = x[n] @ C12T.  16 nodes/block, 4 nodes/thread
// so each (C0T,C12T) element read feeds 8 FMAs.
__global__ void gemm_kernel(const float* __restrict__ x,
                            const float* __restrict__ C0T,
                            const float* __restrict__ C12T,
                            float* __restrict__ out,
                            float* __restrict__ y, int N) {
    __shared__ float xs[16][N_IN];
    int base = blockIdx.x * 16;
    // cooperative load: 16 rows x 32 float4 = 512 float4 by 256 threads
    for (int f = threadIdx.x; f < 16 * 32; f += 256) {
        int row = f >> 5;
        int node = base + row;
        float4 v = make_float4(0.f, 0.f, 0.f, 0.f);
        if (node < N) v = ((const float4*)(x + (size_t)node * N_IN))[f & 31];
        ((float4*)xs)[f] = v;
    }
    __syncthreads();

    int li = threadIdx.x >> 6;   // 0..3 -> node group
    int j  = threadIdx.x & 63;   // output dim
    float a0[4]  = {0.f, 0.f, 0.f, 0.f};
    float a12[4] = {0.f, 0.f, 0.f, 0.f};
    #pragma unroll 4
    for (int i = 0; i < N_IN; ++i) {
        float c0  = C0T[i * N_OUT + j];
        float c12 = C12T[i * N_OUT + j];
        #pragma unroll
        for (int m = 0; m < 4; ++m) {
            float xv = xs[li * 4 + m][i];
            a0[m]  += xv * c0;
            a12[m] += xv * c12;
        }
    }
    #pragma unroll
    for (int m = 0; m < 4; ++m) {
        int node = base + li * 4 + m;
        if (node < N) {
            out[(size_t)node * N_OUT + j] = a0[m];
            y[(size_t)node * N_OUT + j]   = a12[m];
        }
    }
}

// one wave per edge: out[col][j] += norm * y[row][j]
__global__ void scatter_kernel(const int* __restrict__ ei,
                               const float* __restrict__ dis,
                               const float* __restrict__ y,
                               float* __restrict__ out, int E) {
    int e = blockIdx.x * 4 + (threadIdx.x >> 6);
    int j = threadIdx.x & 63;
    if (e >= E) return;
    int r = ei[e];
    int c = ei[E + e];
    float norm = dis[r] * dis[c];
    atomicAdd(&out[(size_t)c * N_OUT + j], norm * y[(size_t)r * N_OUT + j]);
}

extern "C" void kernel_launch(void* const* d_in, const int* in_sizes, int n_in,
                              void* d_out, int out_size, void* d_ws, size_t ws_size,
                              hipStream_t stream) {
    const float* x   = (const float*)d_in[0];
    const int*   ei  = (const int*)d_in[1];
    const float* W0  = (const float*)d_in[2];
    const float* W1  = (const float*)d_in[3];
    const float* W2  = (const float*)d_in[4];
    const float* Wfc = (const float*)d_in[5];
    float* out = (float*)d_out;
    int N = in_sizes[0] / N_IN;
    int E = in_sizes[1] / 2;

    float* ws   = (float*)d_ws;
    float* C0T  = ws;              // 8192 floats
    float* C12T = ws + 8192;       // 8192 floats
    float* dis  = ws + 16384;      // N floats (deg, then deg^-1/2 in place)
    float* y    = ws + 16384 + N;  // N*64 floats

    hipMemsetAsync(dis, 0, (size_t)N * sizeof(float), stream);
    combine_weights<<<(N_IN * N_OUT + 255) / 256, 256, 0, stream>>>(W0, W1, W2, Wfc, C0T, C12T);
    degree_kernel<<<(E + 255) / 256, 256, 0, stream>>>(ei, dis, E);
    rsqrt_kernel<<<(N + 255) / 256, 256, 0, stream>>>(dis, N);
    gemm_kernel<<<(N + 15) / 16, 256, 0, stream>>>(x, C0T, C12T, out, y, N);
    scatter_kernel<<<(E + 3) / 4, 256, 0, stream>>>(ei, dis, y, out, E);
}

// Round 3
// 292.079 us; speedup vs baseline: 1.2311x; 1.2311x over previous
//
#include <hip/hip_runtime.h>

#define N_IN  128
#define N_OUT 64

// C0T[i][o] = sum_k Wfc[o][k] * W0[k][i]; C12T folds W1,W2 branches of Wfc.
__global__ void combine_weights(const float* __restrict__ W0,
                                const float* __restrict__ W1,
                                const float* __restrict__ W2,
                                const float* __restrict__ Wfc,
                                float* __restrict__ C0T,
                                float* __restrict__ C12T) {
    int t = blockIdx.x * blockDim.x + threadIdx.x;   // 8192 threads
    if (t >= N_IN * N_OUT) return;
    int o = t & (N_OUT - 1);
    int i = t >> 6;
    float a0 = 0.f, a12 = 0.f;
    for (int k = 0; k < 128; ++k) {
        a0  += Wfc[o * 384 + k]       * W0[k * N_IN + i];
        a12 += Wfc[o * 384 + 128 + k] * W1[k * N_IN + i]
             + Wfc[o * 384 + 256 + k] * W2[k * N_IN + i];
    }
    C0T[i * N_OUT + o]  = a0;
    C12T[i * N_OUT + o] = a12;
}

__global__ void degree_kernel(const int* __restrict__ ei,
                              int* __restrict__ cnt, int E) {
    int e = blockIdx.x * blockDim.x + threadIdx.x;
    if (e < E) atomicAdd(&cnt[ei[E + e]], 1);
}

// ---- 3-kernel exclusive scan over cnt[N] -> offs[N] ----
__global__ void scan1_kernel(const int* __restrict__ cnt,
                             int* __restrict__ offs,
                             int* __restrict__ bsum, int N) {
    __shared__ int s[256];
    int g = blockIdx.x * 256 + threadIdx.x;
    int v = (g < N) ? cnt[g] : 0;
    int x = v;
    s[threadIdx.x] = x;
    __syncthreads();
    for (int off = 1; off < 256; off <<= 1) {
        int t = (threadIdx.x >= off) ? s[threadIdx.x - off] : 0;
        __syncthreads();
        x += t;
        s[threadIdx.x] = x;
        __syncthreads();
    }
    if (g < N) offs[g] = x - v;                       // exclusive within block
    if (threadIdx.x == 255) bsum[blockIdx.x] = x;     // block total
}

__global__ void scan2_kernel(const int* __restrict__ bsum,
                             int* __restrict__ bpre, int nb) {
    __shared__ int s[256];
    int v = (threadIdx.x < nb) ? bsum[threadIdx.x] : 0;
    int x = v;
    s[threadIdx.x] = x;
    __syncthreads();
    for (int off = 1; off < 256; off <<= 1) {
        int t = (threadIdx.x >= off) ? s[threadIdx.x - off] : 0;
        __syncthreads();
        x += t;
        s[threadIdx.x] = x;
        __syncthreads();
    }
    if (threadIdx.x < nb) bpre[threadIdx.x] = x - v;  // exclusive
}

__global__ void scan3_kernel(int* __restrict__ offs, int* __restrict__ cursor,
                             const int* __restrict__ cnt,
                             const int* __restrict__ bpre,
                             float* __restrict__ dis, int N) {
    int g = blockIdx.x * 256 + threadIdx.x;
    if (g >= N) return;
    int o = offs[g] + bpre[blockIdx.x];
    offs[g] = o;
    cursor[g] = o;
    int c = cnt[g];
    dis[g] = c > 0 ? rsqrtf((float)c) : 0.f;
}

// CSR build: srow[segment of col c] = row indices of edges into c
__global__ void fill_kernel(const int* __restrict__ ei,
                            int* __restrict__ cursor,
                            int* __restrict__ srow, int E) {
    int e = blockIdx.x * blockDim.x + threadIdx.x;
    if (e >= E) return;
    int c = ei[E + e];
    int p = atomicAdd(&cursor[c], 1);
    srow[p] = ei[e];
}

// out[n] = x[n] @ C0T;  z[n] = dis[n] * (x[n] @ C12T)
__global__ void gemm_kernel(const float* __restrict__ x,
                            const float* __restrict__ C0T,
                            const float* __restrict__ C12T,
                            const float* __restrict__ dis,
                            float* __restrict__ out,
                            float* __restrict__ z, int N) {
    __shared__ float xs[16][N_IN];
    int base = blockIdx.x * 16;
    for (int f = threadIdx.x; f < 16 * 32; f += 256) {
        int row = f >> 5;
        int node = base + row;
        float4 v = make_float4(0.f, 0.f, 0.f, 0.f);
        if (node < N) v = ((const float4*)(x + (size_t)node * N_IN))[f & 31];
        ((float4*)xs)[f] = v;
    }
    __syncthreads();

    int li = threadIdx.x >> 6;   // node group 0..3
    int j  = threadIdx.x & 63;   // output dim
    float a0[4]  = {0.f, 0.f, 0.f, 0.f};
    float a12[4] = {0.f, 0.f, 0.f, 0.f};
    #pragma unroll 4
    for (int i = 0; i < N_IN; ++i) {
        float c0  = C0T[i * N_OUT + j];
        float c12 = C12T[i * N_OUT + j];
        #pragma unroll
        for (int m = 0; m < 4; ++m) {
            float xv = xs[li * 4 + m][i];
            a0[m]  += xv * c0;
            a12[m] += xv * c12;
        }
    }
    #pragma unroll
    for (int m = 0; m < 4; ++m) {
        int node = base + li * 4 + m;
        if (node < N) {
            float dn = dis[node];
            out[(size_t)node * N_OUT + j] = a0[m];
            z[(size_t)node * N_OUT + j]  = dn * a12[m];
        }
    }
}

// one wave per destination node: out[c] += dis[c] * sum_{r in seg(c)} z[r]
__global__ __launch_bounds__(256) void gather_kernel(
        const int* __restrict__ offs, const int* __restrict__ cnt,
        const int* __restrict__ srow, const float* __restrict__ z,
        const float* __restrict__ dis, float* __restrict__ out, int N) {
    int node = blockIdx.x * 4 + (threadIdx.x >> 6);
    if (node >= N) return;
    int j = threadIdx.x & 63;
    int start = offs[node];
    int deg = cnt[node];
    float acc = 0.f;
    for (int k0 = 0; k0 < deg; k0 += 64) {
        int m = deg - k0;
        if (m > 64) m = 64;
        int idx = (k0 + j < deg) ? srow[start + k0 + j] : 0;  // coalesced
        for (int kk = 0; kk < m; ++kk) {
            int r = __shfl(idx, kk);
            acc += z[(size_t)r * N_OUT + j];
        }
    }
    if (deg > 0)
        out[(size_t)node * N_OUT + j] += dis[node] * acc;
}

extern "C" void kernel_launch(void* const* d_in, const int* in_sizes, int n_in,
                              void* d_out, int out_size, void* d_ws, size_t ws_size,
                              hipStream_t stream) {
    const float* x   = (const float*)d_in[0];
    const int*   ei  = (const int*)d_in[1];
    const float* W0  = (const float*)d_in[2];
    const float* W1  = (const float*)d_in[3];
    const float* W2  = (const float*)d_in[4];
    const float* Wfc = (const float*)d_in[5];
    float* out = (float*)d_out;
    int N = in_sizes[0] / N_IN;
    int E = in_sizes[1] / 2;
    int NB = (N + 255) / 256;

    float* ws     = (float*)d_ws;
    float* C0T    = ws;                     // 8192 f
    float* C12T   = C0T + 8192;             // 8192 f
    float* dis    = C12T + 8192;            // N f
    int*   cnt    = (int*)(dis + N);        // N i
    int*   offs   = cnt + N;                // N i
    int*   cursor = offs + N;               // N i
    int*   bsum   = cursor + N;             // 256 i
    int*   bpre   = bsum + 256;             // 256 i
    int*   srow   = bpre + 256;             // E i
    float* z      = (float*)(srow + E);     // N*64 f

    hipMemsetAsync(cnt, 0, (size_t)N * sizeof(int), stream);
    combine_weights<<<(N_IN * N_OUT + 255) / 256, 256, 0, stream>>>(W0, W1, W2, Wfc, C0T, C12T);
    degree_kernel<<<(E + 255) / 256, 256, 0, stream>>>(ei, cnt, E);
    scan1_kernel<<<NB, 256, 0, stream>>>(cnt, offs, bsum, N);
    scan2_kernel<<<1, 256, 0, stream>>>(bsum, bpre, NB);
    scan3_kernel<<<NB, 256, 0, stream>>>(offs, cursor, cnt, bpre, dis, N);
    fill_kernel<<<(E + 255) / 256, 256, 0, stream>>>(ei, cursor, srow, E);
    gemm_kernel<<<(N + 15) / 16, 256, 0, stream>>>(x, C0T, C12T, dis, out, z, N);
    gather_kernel<<<(N + 3) / 4, 256, 0, stream>>>(offs, cnt, srow, z, dis, out, N);
}

// Round 4
// 278.545 us; speedup vs baseline: 1.2909x; 1.0486x over previous
//
#include <hip/hip_runtime.h>
#include <hip/hip_bf16.h>

#define N_IN  128
#define N_OUT 64

// C = folded weights, k-split x4 across blocks, accumulated via f32 atomics
// (C0T/C12T zeroed by the memset in kernel_launch).
__global__ void combine_weights(const float* __restrict__ W0,
                                const float* __restrict__ W1,
                                const float* __restrict__ W2,
                                const float* __restrict__ Wfc,
                                float* __restrict__ C0T,
                                float* __restrict__ C12T) {
    int t = blockIdx.x * blockDim.x + threadIdx.x;   // 32768 threads
    if (t >= N_IN * N_OUT * 4) return;
    int q = t >> 13;          // k-quarter 0..3
    int s = t & 8191;
    int o = s & (N_OUT - 1);
    int i = s >> 6;
    float a0 = 0.f, a12 = 0.f;
    for (int k = q * 32; k < q * 32 + 32; ++k) {
        a0  += Wfc[o * 384 + k]       * W0[k * N_IN + i];
        a12 += Wfc[o * 384 + 128 + k] * W1[k * N_IN + i]
             + Wfc[o * 384 + 256 + k] * W2[k * N_IN + i];
    }
    atomicAdd(&C0T[i * N_OUT + o], a0);
    atomicAdd(&C12T[i * N_OUT + o], a12);
}

__global__ void degree_kernel(const int* __restrict__ ei,
                              int* __restrict__ cnt, int E) {
    int e = blockIdx.x * blockDim.x + threadIdx.x;
    if (e < E) atomicAdd(&cnt[ei[E + e]], 1);
}

// ---- 3-kernel exclusive scan over cnt[N] -> offs[N] ----
__global__ void scan1_kernel(const int* __restrict__ cnt,
                             int* __restrict__ offs,
                             int* __restrict__ bsum, int N) {
    __shared__ int s[256];
    int g = blockIdx.x * 256 + threadIdx.x;
    int v = (g < N) ? cnt[g] : 0;
    int x = v;
    s[threadIdx.x] = x;
    __syncthreads();
    for (int off = 1; off < 256; off <<= 1) {
        int t = (threadIdx.x >= off) ? s[threadIdx.x - off] : 0;
        __syncthreads();
        x += t;
        s[threadIdx.x] = x;
        __syncthreads();
    }
    if (g < N) offs[g] = x - v;
    if (threadIdx.x == 255) bsum[blockIdx.x] = x;
}

__global__ void scan2_kernel(const int* __restrict__ bsum,
                             int* __restrict__ bpre, int nb) {
    __shared__ int s[256];
    int v = (threadIdx.x < nb) ? bsum[threadIdx.x] : 0;
    int x = v;
    s[threadIdx.x] = x;
    __syncthreads();
    for (int off = 1; off < 256; off <<= 1) {
        int t = (threadIdx.x >= off) ? s[threadIdx.x - off] : 0;
        __syncthreads();
        x += t;
        s[threadIdx.x] = x;
        __syncthreads();
    }
    if (threadIdx.x < nb) bpre[threadIdx.x] = x - v;
}

__global__ void scan3_kernel(int* __restrict__ offs, int* __restrict__ cursor,
                             const int* __restrict__ cnt,
                             const int* __restrict__ bpre,
                             float* __restrict__ dis, int N) {
    int g = blockIdx.x * 256 + threadIdx.x;
    if (g >= N) return;
    int o = offs[g] + bpre[blockIdx.x];
    offs[g] = o;
    cursor[g] = o;
    int c = cnt[g];
    dis[g] = c > 0 ? rsqrtf((float)c) : 0.f;
}

// CSR build. atomicExch instead of plain store: the atomic path writes HBM at
// dword granularity (R2 evidence: 51.2M atomics -> exactly 204.8MB), while
// scattered plain stores cost a full 64B line each (R3: 800k stores -> 52.9MB).
__global__ void fill_kernel(const int* __restrict__ ei,
                            int* __restrict__ cursor,
                            int* __restrict__ srow, int E) {
    int e = blockIdx.x * blockDim.x + threadIdx.x;
    if (e >= E) return;
    int c = ei[E + e];
    int p = atomicAdd(&cursor[c], 1);
    atomicExch(&srow[p], ei[e]);
}

// out[n] = x[n] @ C0T;  z[n] = bf16( dis[n] * (x[n] @ C12T) )
__global__ void gemm_kernel(const float* __restrict__ x,
                            const float* __restrict__ C0T,
                            const float* __restrict__ C12T,
                            const float* __restrict__ dis,
                            float* __restrict__ out,
                            __hip_bfloat16* __restrict__ z, int N) {
    __shared__ float xs[16][N_IN];
    int base = blockIdx.x * 16;
    for (int f = threadIdx.x; f < 16 * 32; f += 256) {
        int row = f >> 5;
        int node = base + row;
        float4 v = make_float4(0.f, 0.f, 0.f, 0.f);
        if (node < N) v = ((const float4*)(x + (size_t)node * N_IN))[f & 31];
        ((float4*)xs)[f] = v;
    }
    __syncthreads();

    int li = threadIdx.x >> 6;   // node group 0..3
    int j  = threadIdx.x & 63;   // output dim
    float a0[4]  = {0.f, 0.f, 0.f, 0.f};
    float a12[4] = {0.f, 0.f, 0.f, 0.f};
    #pragma unroll 4
    for (int i = 0; i < N_IN; ++i) {
        float c0  = C0T[i * N_OUT + j];
        float c12 = C12T[i * N_OUT + j];
        #pragma unroll
        for (int m = 0; m < 4; ++m) {
            float xv = xs[li * 4 + m][i];
            a0[m]  += xv * c0;
            a12[m] += xv * c12;
        }
    }
    #pragma unroll
    for (int m = 0; m < 4; ++m) {
        int node = base + li * 4 + m;
        if (node < N) {
            float dn = dis[node];
            out[(size_t)node * N_OUT + j] = a0[m];
            z[((size_t)node << 6) + j] = __float2bfloat16(dn * a12[m]);
        }
    }
}

// One wave per destination node; 2 edges per iteration (one per half-wave).
// Each lane loads a bf16x2 dword: 256B/wave-instruction covers two z rows.
__global__ __launch_bounds__(256) void gather_kernel(
        const int* __restrict__ offs, const int* __restrict__ cnt,
        const int* __restrict__ srow, const __hip_bfloat16* __restrict__ z,
        const float* __restrict__ dis, float* __restrict__ out, int N) {
    int node = blockIdx.x * 4 + (threadIdx.x >> 6);
    if (node >= N) return;
    int lane = threadIdx.x & 63;
    int sub  = lane >> 5;        // which edge of the pair
    int jj   = lane & 31;        // dim-pair index (dims 2jj, 2jj+1)
    int start = offs[node];
    int deg   = cnt[node];
    float a0 = 0.f, a1 = 0.f;
    for (int k0 = 0; k0 < deg; k0 += 64) {
        int m = deg - k0; if (m > 64) m = 64;
        int idx = (lane < m) ? srow[start + k0 + lane] : 0;  // coalesced
        int np = (m + 1) >> 1;
        for (int kk = 0; kk < np; ++kk) {
            int r = __shfl(idx, 2 * kk + sub);
            bool ok = (2 * kk + sub) < m;
            unsigned u = ((const unsigned*)(z + ((size_t)r << 6)))[jj];
            float f0 = __uint_as_float(u << 16);
            float f1 = __uint_as_float(u & 0xffff0000u);
            if (ok) { a0 += f0; a1 += f1; }
        }
    }
    a0 += __shfl_xor(a0, 32);
    a1 += __shfl_xor(a1, 32);
    if (sub == 0 && deg > 0) {
        float dn = dis[node];
        float2* op = (float2*)(out + ((size_t)node << 6));
        float2 v = op[jj];
        v.x += dn * a0;
        v.y += dn * a1;
        op[jj] = v;
    }
}

extern "C" void kernel_launch(void* const* d_in, const int* in_sizes, int n_in,
                              void* d_out, int out_size, void* d_ws, size_t ws_size,
                              hipStream_t stream) {
    const float* x   = (const float*)d_in[0];
    const int*   ei  = (const int*)d_in[1];
    const float* W0  = (const float*)d_in[2];
    const float* W1  = (const float*)d_in[3];
    const float* W2  = (const float*)d_in[4];
    const float* Wfc = (const float*)d_in[5];
    float* out = (float*)d_out;
    int N = in_sizes[0] / N_IN;
    int E = in_sizes[1] / 2;
    int NB = (N + 255) / 256;

    float* ws     = (float*)d_ws;
    float* C0T    = ws;                     // 8192 f   (zeroed)
    float* C12T   = C0T + 8192;             // 8192 f   (zeroed)
    int*   cnt    = (int*)(C12T + 8192);    // N i      (zeroed)
    int*   offs   = cnt + N;                // N i
    int*   cursor = offs + N;               // N i
    int*   bsum   = cursor + N;             // 256 i
    int*   bpre   = bsum + 256;             // 256 i
    int*   srow   = bpre + 256;             // E i
    float* dis    = (float*)(srow + E);     // N f
    __hip_bfloat16* z = (__hip_bfloat16*)(dis + N);   // N*64 bf16

    hipMemsetAsync(ws, 0, (size_t)(16384 + N) * sizeof(float), stream);
    combine_weights<<<(N_IN * N_OUT * 4 + 255) / 256, 256, 0, stream>>>(W0, W1, W2, Wfc, C0T, C12T);
    degree_kernel<<<(E + 255) / 256, 256, 0, stream>>>(ei, cnt, E);
    scan1_kernel<<<NB, 256, 0, stream>>>(cnt, offs, bsum, N);
    scan2_kernel<<<1, 256, 0, stream>>>(bsum, bpre, NB);
    scan3_kernel<<<NB, 256, 0, stream>>>(offs, cursor, cnt, bpre, dis, N);
    fill_kernel<<<(E + 255) / 256, 256, 0, stream>>>(ei, cursor, srow, E);
    gemm_kernel<<<(N + 15) / 16, 256, 0, stream>>>(x, C0T, C12T, dis, out, z, N);
    gather_kernel<<<(N + 3) / 4, 256, 0, stream>>>(offs, cnt, srow, z, dis, out, N);
}